// Round 6
// baseline (1934.686 us; speedup 1.0000x reference)
//
#include <hip/hip_runtime.h>

#define BATCH 32
#define NPTS  262144
#define KSAMP 256
#define NF    10
#define INDIM 60
#define HID   768

#define NBLK_PER_B 8
#define SLICE (NPTS/NBLK_PER_B)   // 32768 points per block (one CU)
// ALL 32 pts/thread register-resident: 96 coord floats + d[32] (unified VGPR/AGPR file)

#define PI_F 3.14159274101257324f  // float(math.pi)

// Static device scratch (rewritten every call before use)
__device__ float g_samp[BATCH*KSAMP*3];
__device__ float g_enc[(size_t)BATCH*KSAMP*INDIM];
__device__ float g_Wt[INDIM*HID];
__device__ unsigned long long g_slot[BATCH][2][NBLK_PER_B]; // [parity][slice], tag k in [63:56]

__device__ __forceinline__ float san(float v){
  float m = v*0.0f;                 // finite -> 0, inf/nan -> nan (no fast-math fold)
  return (m == 0.0f) ? v : 0.0f;
}

// ---------------- W transpose + slot clear ----------------
__global__ __launch_bounds__(256) void wtrans(const float* __restrict__ W){
  int idx = blockIdx.x*256 + threadIdx.x;   // < 60*768 = 46080
  int d = idx / HID;
  int h = idx - d*HID;
  g_Wt[idx] = W[h*INDIM + d];
  if (blockIdx.x == 0 && threadIdx.x < 256){
    ((unsigned long long*)g_slot)[threadIdx.x*2+0] = 0ull;
    ((unsigned long long*)g_slot)[threadIdx.x*2+1] = 0ull;
  }
}

// ---------------- FPS ----------------
// Bit-exact vs reference: d = ((x-lx)^2 + (y-ly)^2) + (z-lz)^2, rn each step, no FMA.
__device__ __forceinline__ float dist3(float x,float y,float z,float lx,float ly,float lz){
  float dx=__fsub_rn(x,lx), dy=__fsub_rn(y,ly), dz=__fsub_rn(z,lz);
  return __fadd_rn(__fadd_rn(__fmul_rn(dx,dx),__fmul_rn(dy,dy)),__fmul_rn(dz,dz));
}

__global__ __launch_bounds__(1024, 4) void fps_kernel(const float* __restrict__ pc){
  __shared__ float s_val[2][16];
  __shared__ int   s_idx[2][16];
  __shared__ float s_res[2][3];
  __shared__ int   s_flag[2];

  // XCD-locality swizzle: assuming round-robin blockIdx%8 -> XCD, this puts
  // all 8 slices of a batch on ONE XCD (4 batches per XCD). Perf-only heuristic.
  const int blk = blockIdx.x;
  const int b   = (blk & 7) + 8*(blk >> 6);   // batch
  const int s   = (blk >> 3) & 7;             // slice
  const int tid = threadIdx.x;
  const int lane = tid & 63, wave = tid >> 6;
  const size_t bN = (size_t)b*NPTS;
  const int soff = s*SLICE;

  // ---- one-time load: all 8 groups (32 pts) into registers, sanitized, from AoS pc ----
  float rx[32], ry[32], rz[32];
#pragma unroll
  for (int j=0;j<8;j++){
    int p0 = soff + j*4096 + tid*4;
    const float* src = pc + (bN + p0)*3;
    float4 A = *(const float4*)(src);
    float4 Bv= *(const float4*)(src+4);
    float4 C = *(const float4*)(src+8);
    float v[12] = {A.x,A.y,A.z,A.w,Bv.x,Bv.y,Bv.z,Bv.w,C.x,C.y,C.z,C.w};
#pragma unroll
    for (int q=0;q<12;q++) v[q] = san(v[q]);
#pragma unroll
    for (int c=0;c<4;c++){ rx[j*4+c]=v[3*c]; ry[j*4+c]=v[3*c+1]; rz[j*4+c]=v[3*c+2]; }
  }

  float d[32];
#pragma unroll
  for (int i=0;i<32;i++) d[i] = __builtin_huge_valf();

  // first sample = sanitized point 0 (uniform scalar loads)
  float lx = san(pc[bN*3+0]), ly = san(pc[bN*3+1]), lz = san(pc[bN*3+2]);
  if (s==0 && tid<3) g_samp[(size_t)b*KSAMP*3 + tid] = san(pc[bN*3 + tid]);
  if (tid==0){ s_flag[0]=0; s_flag[1]=0; }
  __syncthreads();

  for (int k=1; k<KSAMP; k++){
    const int par = k & 1;
    float bestv = -1.0f; int besti = 0;
    // pure-register scan: no memory ops, no waits
#pragma unroll
    for (int i=0;i<32;i++){
      float dd = dist3(rx[i], ry[i], rz[i], lx, ly, lz);
      float nd = fminf(d[i], dd);
      d[i] = nd;
      if (nd > bestv){ bestv = nd; besti = soff + (i>>2)*4096 + tid*4 + (i&3); }
    }

    // intra-wave argmax (first-index tie-break)
#pragma unroll
    for (int off=32; off; off>>=1){
      float ov = __shfl_down(bestv, off);
      int   oi = __shfl_down(besti, off);
      if (ov > bestv || (ov == bestv && oi < besti)){ bestv=ov; besti=oi; }
    }
    if (lane==0){ s_val[par][wave]=bestv; s_idx[par][wave]=besti; }
    __syncthreads();   // all 16 wave candidates visible

    if (wave==0){
      // 16-lane cross-wave reduce (butterfly -> all lanes hold block candidate)
      float bv = s_val[par][lane & 15]; int bi = s_idx[par][lane & 15];
#pragma unroll
      for (int m=8; m; m>>=1){
        float ov = __shfl_xor(bv, m);
        int   oi = __shfl_xor(bi, m);
        if (ov > bv || (ov == bv && oi < bi)){ bv=ov; bi=oi; }
      }
      // publish packed candidate: [k:8][val:32][0xFFFFFF^idx:24]
      // RELAXED is sufficient: the tagged u64 is self-contained; winner
      // coords come from read-only pc; parity buffer bounds skew to 1 iter.
      unsigned long long key = ((unsigned long long)(unsigned)k << 56)
                             | ((unsigned long long)__float_as_uint(bv) << 24)
                             | (unsigned long long)(0xFFFFFFu ^ (unsigned)bi);
      if (lane==0)
        __hip_atomic_store(&g_slot[b][par][s], key, __ATOMIC_RELAXED, __HIP_MEMORY_SCOPE_AGENT);
      // parallel poll: lane q watches slice q; s_sleep backoff keeps LLC
      // bank pressure off the publisher's store.
      unsigned long long pay = 0;
      if (lane < NBLK_PER_B){
        unsigned long long v;
        for (;;){
          v = __hip_atomic_load(&g_slot[b][par][lane], __ATOMIC_RELAXED, __HIP_MEMORY_SCOPE_AGENT);
          if ((unsigned)(v >> 56) == (unsigned)k) break;
          __builtin_amdgcn_s_sleep(1);
        }
        pay = v & 0x00FFFFFFFFFFFFFFull;
      }
      // 8-lane max butterfly on payload (u64 via 2x32 shuffles)
#pragma unroll
      for (int m=4; m; m>>=1){
        unsigned lo = (unsigned)pay, hi = (unsigned)(pay >> 32);
        unsigned lo2 = __shfl_xor(lo, m), hi2 = __shfl_xor(hi, m);
        unsigned long long o = ((unsigned long long)hi2 << 32) | lo2;
        if (o > pay) pay = o;
      }
      int w = (int)(0xFFFFFFu ^ (unsigned)(pay & 0xFFFFFFu));
      if (lane < 3){
        float cv = san(pc[(bN + (size_t)w)*3 + lane]);
        s_res[par][lane] = cv;
        if (s==0) g_samp[((size_t)b*KSAMP + k)*3 + lane] = cv;
      }
      // release: LDS writes above ordered before flag (workgroup scope)
      if (lane==0)
        __hip_atomic_store(&s_flag[par], k, __ATOMIC_RELEASE, __HIP_MEMORY_SCOPE_WORKGROUP);
      lx = s_res[par][0]; ly = s_res[par][1]; lz = s_res[par][2];
    } else {
      // spin on LDS flag (broadcast read) -> resume scan without block barrier,
      // overlapping wave0's publish/poll tail with our next scan
      while (__hip_atomic_load(&s_flag[par], __ATOMIC_ACQUIRE, __HIP_MEMORY_SCOPE_WORKGROUP) != k)
        ;
      lx = s_res[par][0]; ly = s_res[par][1]; lz = s_res[par][2];
    }
  }
}

// ---------------- normalize + Fourier encode ----------------
template<int OP>  // 0 sum, 1 max, 2 min
__device__ __forceinline__ float blk_red(float v, float* s4){
  int tid = threadIdx.x;
#pragma unroll
  for (int off=32; off; off>>=1){
    float o = __shfl_down(v, off);
    v = (OP==0) ? v+o : ((OP==1) ? fmaxf(v,o) : fminf(v,o));
  }
  if ((tid&63)==0) s4[tid>>6] = v;
  __syncthreads();
  float r0=s4[0], r1=s4[1], r2=s4[2], r3=s4[3];
  float r = (OP==0) ? ((r0+r1)+(r2+r3))
          : ((OP==1) ? fmaxf(fmaxf(r0,r1),fmaxf(r2,r3))
                     : fminf(fminf(r0,r1),fminf(r2,r3)));
  __syncthreads();
  return r;
}

__global__ __launch_bounds__(256) void norm_encode(){
  __shared__ float s4[4];
  int b = blockIdx.x, k = threadIdx.x;
  const float* sp = &g_samp[((size_t)b*KSAMP + k)*3];
  float x = sp[0], y = sp[1], z = sp[2];

  float cx = blk_red<0>(x, s4) * (1.0f/KSAMP);
  float cy = blk_red<0>(y, s4) * (1.0f/KSAMP);
  float cz = blk_red<0>(z, s4) * (1.0f/KSAMP);

  float ux = __fsub_rn(x,cx), uy = __fsub_rn(y,cy), uz = __fsub_rn(z,cz);

  float mxx = blk_red<1>(ux, s4), mnx = blk_red<2>(ux, s4);
  float mxy = blk_red<1>(uy, s4), mny = blk_red<2>(uy, s4);
  float mxz = blk_red<1>(uz, s4), mnz = blk_red<2>(uz, s4);
  float bx = __fsub_rn(mxx,mnx), by = __fsub_rn(mxy,mny), bz = __fsub_rn(mxz,mnz);
  float md = fmaxf(fmaxf(bx,by),bz);
  float scale = (md > 1e-8f) ? md : 1.0f;

  float n3[3] = { __fdiv_rn(ux,scale), __fdiv_rn(uy,scale), __fdiv_rn(uz,scale) };

  float* e = &g_enc[((size_t)b*KSAMP + k)*INDIM];
#pragma unroll
  for (int c=0;c<3;c++){
    float base = n3[c];
#pragma unroll
    for (int f=0; f<NF; f++){
      float t = __fmul_rn(base, (float)(1<<f));
      float a = __fmul_rn(t, PI_F);
      e[c*2*NF + f*2 + 0] = sinf(a);
      e[c*2*NF + f*2 + 1] = cosf(a);
    }
  }
}

// ---------------- GEMM ----------------
__global__ __launch_bounds__(256) void gemm_kernel(const float* __restrict__ bias,
                                                   float* __restrict__ out){
  __shared__ float s_enc[4*INDIM];
  int blk = blockIdx.x, tid = threadIdx.x;
  int row0 = blk*4;                         // 4 (b,k) rows per block
  if (tid < 4*INDIM) s_enc[tid] = g_enc[(size_t)row0*INDIM + tid];
  __syncthreads();

  float acc[4][3] = {};
  for (int d=0; d<INDIM; d++){
    float w0 = g_Wt[d*HID + tid];
    float w1 = g_Wt[d*HID + tid + 256];
    float w2 = g_Wt[d*HID + tid + 512];
#pragma unroll
    for (int r=0;r<4;r++){
      float ev = s_enc[r*INDIM + d];
      acc[r][0] = fmaf(ev, w0, acc[r][0]);
      acc[r][1] = fmaf(ev, w1, acc[r][1]);
      acc[r][2] = fmaf(ev, w2, acc[r][2]);
    }
  }
  float b0=bias[tid], b1=bias[tid+256], b2=bias[tid+512];
#pragma unroll
  for (int r=0;r<4;r++){
    size_t o = (size_t)(row0+r)*HID;
    out[o+tid]     = acc[r][0]+b0;
    out[o+tid+256] = acc[r][1]+b1;
    out[o+tid+512] = acc[r][2]+b2;
  }
}

// ---------------- launch ----------------
extern "C" void kernel_launch(void* const* d_in, const int* in_sizes, int n_in,
                              void* d_out, int out_size, void* d_ws, size_t ws_size,
                              hipStream_t stream){
  const float* pc   = (const float*)d_in[0];
  const float* W    = (const float*)d_in[1];
  const float* bias = (const float*)d_in[2];
  float* out = (float*)d_out;

  wtrans<<<(INDIM*HID)/256, 256, 0, stream>>>(W);

  void* args[] = { (void*)&pc };
  hipLaunchCooperativeKernel((void*)fps_kernel, dim3(BATCH*NBLK_PER_B), dim3(1024),
                             args, 0, stream);

  norm_encode<<<BATCH, KSAMP, 0, stream>>>();
  gemm_kernel<<<(BATCH*KSAMP)/4, 256, 0, stream>>>(bias, out);
}

// Round 7
// 1508.938 us; speedup vs baseline: 1.2822x; 1.2822x over previous
//
#include <hip/hip_runtime.h>

#define BATCH 32
#define NPTS  262144
#define KSAMP 256
#define NF    10
#define INDIM 60
#define HID   768

#define NBLK_PER_B 8
#define SLICE (NPTS/NBLK_PER_B)   // 32768 points per block (one CU)
// per-thread point layout: 8 groups of 4 pts
//   j=0..3  -> registers (16 pts, 48 VGPRs)   [round-5 proven split]
//   j=4..6  -> LDS       (12 pts, 144 KB)
//   j=7     -> global SoA (4 pts, 48 KB/CU, L2-resident)
#define REG_G 4
#define LDS_G 3

#define PI_F 3.14159274101257324f  // float(math.pi)

// Static device scratch (rewritten every call before use)
__device__ float g_px[BATCH*NPTS];   // only group j=7 regions used
__device__ float g_py[BATCH*NPTS];
__device__ float g_pz[BATCH*NPTS];
__device__ float g_samp[BATCH*KSAMP*3];
__device__ float g_enc[(size_t)BATCH*KSAMP*INDIM];
__device__ float g_Wt[INDIM*HID];
__device__ unsigned long long g_slot[BATCH][2][NBLK_PER_B]; // [parity][slice], tag k in [63:56]

__device__ __forceinline__ float san(float v){
  float m = v*0.0f;                 // finite -> 0, inf/nan -> nan (no fast-math fold)
  return (m == 0.0f) ? v : 0.0f;
}

// ---------------- region prepass: sanitize + SoA for global-resident 1/8 ----------------
__global__ __launch_bounds__(256) void region_prepass(const float* __restrict__ pc){
  int bid = blockIdx.x;             // 1024 blocks
  int b   = bid >> 5;               // 32 blocks per batch
  int rem = bid & 31;
  int q   = rem*1024 + threadIdx.x*4;   // 0..32767 region-local (per batch)
  int s   = q >> 12;                    // slice (4096 pts of group 7 per slice)
  int o   = q & 4095;
  int p   = s*SLICE + 7*4096 + o;       // global point index in batch
  const float* src = pc + ((size_t)b*NPTS + p)*3;
  float4 A = *(const float4*)(src);
  float4 Bv= *(const float4*)(src+4);
  float4 C = *(const float4*)(src+8);
  float v[12] = {A.x,A.y,A.z,A.w,Bv.x,Bv.y,Bv.z,Bv.w,C.x,C.y,C.z,C.w};
#pragma unroll
  for (int j=0;j<12;j++) v[j] = san(v[j]);
  size_t base = (size_t)b*NPTS + p;
  *(float4*)(g_px+base) = make_float4(v[0],v[3],v[6],v[9]);
  *(float4*)(g_py+base) = make_float4(v[1],v[4],v[7],v[10]);
  *(float4*)(g_pz+base) = make_float4(v[2],v[5],v[8],v[11]);
}

// ---------------- W transpose + slot clear ----------------
__global__ __launch_bounds__(256) void wtrans(const float* __restrict__ W){
  int idx = blockIdx.x*256 + threadIdx.x;   // < 60*768 = 46080
  int d = idx / HID;
  int h = idx - d*HID;
  g_Wt[idx] = W[h*INDIM + d];
  if (blockIdx.x == 0 && threadIdx.x < 256){
    ((unsigned long long*)g_slot)[threadIdx.x*2+0] = 0ull;
    ((unsigned long long*)g_slot)[threadIdx.x*2+1] = 0ull;
  }
}

// ---------------- FPS ----------------
// Bit-exact vs reference: d = ((x-lx)^2 + (y-ly)^2) + (z-lz)^2, rn each step, no FMA.
__device__ __forceinline__ float dist3(float x,float y,float z,float lx,float ly,float lz){
  float dx=__fsub_rn(x,lx), dy=__fsub_rn(y,ly), dz=__fsub_rn(z,lz);
  return __fadd_rn(__fadd_rn(__fmul_rn(dx,dx),__fmul_rn(dy,dy)),__fmul_rn(dz,dz));
}

__global__ __launch_bounds__(1024, 4) void fps_kernel(const float* __restrict__ pc){
  __shared__ float4 sX[LDS_G*1024], sY[LDS_G*1024], sZ[LDS_G*1024];  // 144 KB
  __shared__ unsigned long long s_cand[2][16];  // per-wave candidate, tag k in [63:56]
  __shared__ float s_res[2][4];                 // winner coords
  __shared__ int   s_flag[2];                   // iteration-complete flag

  // XCD-locality swizzle: assuming round-robin blockIdx%8 -> XCD, this puts
  // all 8 slices of a batch on ONE XCD (4 batches per XCD). Perf-only heuristic.
  const int blk = blockIdx.x;
  const int b   = (blk & 7) + 8*(blk >> 6);   // batch
  const int s   = (blk >> 3) & 7;             // slice
  const int tid = threadIdx.x;
  const int lane = tid & 63, wave = tid >> 6;
  const size_t bN = (size_t)b*NPTS;
  const int soff = s*SLICE;

  // ---- one-time load: regs (j=0..3) and LDS (j=4..6), sanitized, from AoS pc ----
  float rx[REG_G*4], ry[REG_G*4], rz[REG_G*4];
#pragma unroll
  for (int j=0;j<REG_G+LDS_G;j++){
    int p0 = soff + j*4096 + tid*4;
    const float* src = pc + (bN + p0)*3;
    float4 A = *(const float4*)(src);
    float4 Bv= *(const float4*)(src+4);
    float4 C = *(const float4*)(src+8);
    float v[12] = {A.x,A.y,A.z,A.w,Bv.x,Bv.y,Bv.z,Bv.w,C.x,C.y,C.z,C.w};
#pragma unroll
    for (int q=0;q<12;q++) v[q] = san(v[q]);
    if (j < REG_G){
#pragma unroll
      for (int c=0;c<4;c++){ rx[j*4+c]=v[3*c]; ry[j*4+c]=v[3*c+1]; rz[j*4+c]=v[3*c+2]; }
    } else {
      sX[(j-REG_G)*1024+tid] = make_float4(v[0],v[3],v[6],v[9]);
      sY[(j-REG_G)*1024+tid] = make_float4(v[1],v[4],v[7],v[10]);
      sZ[(j-REG_G)*1024+tid] = make_float4(v[2],v[5],v[8],v[11]);
    }
  }

  float d[32];
#pragma unroll
  for (int i=0;i<32;i++) d[i] = __builtin_huge_valf();

  // first sample = sanitized point 0 (uniform scalar loads)
  float lx = san(pc[bN*3+0]), ly = san(pc[bN*3+1]), lz = san(pc[bN*3+2]);
  if (s==0 && tid<3) g_samp[(size_t)b*KSAMP*3 + tid] = san(pc[bN*3 + tid]);
  if (tid==0){ s_flag[0]=0; s_flag[1]=0; }
  if (tid<32) s_cand[tid>>4][tid&15] = 0ull;
  __syncthreads();   // LDS coords + flags visible; the ONLY block barrier

  for (int k=1; k<KSAMP; k++){
    const int par = k & 1;
    // issue global-group loads first (L2-resident region)
    size_t gb = bN + soff + (size_t)7*4096 + tid*4;
    float4 gx = *(const float4*)(g_px+gb);
    float4 gy = *(const float4*)(g_py+gb);
    float4 gz = *(const float4*)(g_pz+gb);

    float bestv = -1.0f; int besti = 0;
#define UPD(DX,DY,DZ,DI,IDX) { \
      float dd_ = dist3(DX,DY,DZ,lx,ly,lz); \
      float nd_ = fminf(d[DI], dd_); \
      d[DI] = nd_; \
      if (nd_ > bestv){ bestv = nd_; besti = (IDX); } }
    // register groups j=0..3
#pragma unroll
    for (int j=0;j<REG_G;j++){
#pragma unroll
      for (int c=0;c<4;c++)
        UPD(rx[j*4+c], ry[j*4+c], rz[j*4+c], j*4+c, soff + j*4096 + tid*4 + c)
    }
    // LDS groups j=4..6 (load just-in-time to limit register liveness)
#pragma unroll
    for (int j=0;j<LDS_G;j++){
      float4 X = sX[j*1024+tid], Y = sY[j*1024+tid], Z = sZ[j*1024+tid];
      float xs[4]={X.x,X.y,X.z,X.w}, ys[4]={Y.x,Y.y,Y.z,Y.w}, zs[4]={Z.x,Z.y,Z.z,Z.w};
#pragma unroll
      for (int c=0;c<4;c++)
        UPD(xs[c], ys[c], zs[c], (REG_G+j)*4+c, soff + (REG_G+j)*4096 + tid*4 + c)
    }
    // global group j=7
    {
      float xs[4]={gx.x,gx.y,gx.z,gx.w}, ys[4]={gy.x,gy.y,gy.z,gy.w}, zs[4]={gz.x,gz.y,gz.z,gz.w};
#pragma unroll
      for (int c=0;c<4;c++)
        UPD(xs[c], ys[c], zs[c], 28+c, soff + 7*4096 + tid*4 + c)
    }
#undef UPD

    // intra-wave argmax (first-index tie-break)
#pragma unroll
    for (int off=32; off; off>>=1){
      float ov = __shfl_down(bestv, off);
      int   oi = __shfl_down(besti, off);
      if (ov > bestv || (ov == bestv && oi < besti)){ bestv=ov; besti=oi; }
    }
    // per-wave candidate publish into LDS: [k:8][val:32][0xFFFFFF^idx:24]
    // (tag inside the same u64 -> ds_write_b64 atomicity carries the protocol;
    //  no barrier needed)
    unsigned long long wkey = ((unsigned long long)(unsigned)k << 56)
                            | ((unsigned long long)__float_as_uint(bestv) << 24)
                            | (unsigned long long)(0xFFFFFFu ^ (unsigned)besti);
    if (lane==0)
      __hip_atomic_store(&s_cand[par][wave], wkey, __ATOMIC_RELAXED, __HIP_MEMORY_SCOPE_WORKGROUP);

    if (wave==0){
      // poll all 16 wave candidates (lane q watches wave q&15)
      unsigned long long v;
      for (;;){
        v = __hip_atomic_load(&s_cand[par][lane & 15], __ATOMIC_RELAXED, __HIP_MEMORY_SCOPE_WORKGROUP);
        if ((unsigned)(v >> 56) == (unsigned)k) break;
      }
      unsigned long long pay = v & 0x00FFFFFFFFFFFFFFull;
      // 16-lane max butterfly (u64 via 2x32 shuffles); m=8..1 stays within 16-groups
#pragma unroll
      for (int m=8; m; m>>=1){
        unsigned lo = (unsigned)pay, hi = (unsigned)(pay >> 32);
        unsigned lo2 = __shfl_xor(lo, m), hi2 = __shfl_xor(hi, m);
        unsigned long long o = ((unsigned long long)hi2 << 32) | lo2;
        if (o > pay) pay = o;
      }
      // publish block candidate to global slot (RELAXED: self-contained tagged u64)
      unsigned long long key = ((unsigned long long)(unsigned)k << 56) | pay;
      if (lane==0)
        __hip_atomic_store(&g_slot[b][par][s], key, __ATOMIC_RELAXED, __HIP_MEMORY_SCOPE_AGENT);
      // parallel poll: lane q watches slice q; s_sleep backoff keeps LLC
      // bank pressure off the publisher's store.
      unsigned long long gpay = 0;
      if (lane < NBLK_PER_B){
        unsigned long long gv;
        for (;;){
          gv = __hip_atomic_load(&g_slot[b][par][lane], __ATOMIC_RELAXED, __HIP_MEMORY_SCOPE_AGENT);
          if ((unsigned)(gv >> 56) == (unsigned)k) break;
          __builtin_amdgcn_s_sleep(1);
        }
        gpay = gv & 0x00FFFFFFFFFFFFFFull;
      }
      // 8-lane max butterfly
#pragma unroll
      for (int m=4; m; m>>=1){
        unsigned lo = (unsigned)gpay, hi = (unsigned)(gpay >> 32);
        unsigned lo2 = __shfl_xor(lo, m), hi2 = __shfl_xor(hi, m);
        unsigned long long o = ((unsigned long long)hi2 << 32) | lo2;
        if (o > gpay) gpay = o;
      }
      int w = (int)(0xFFFFFFu ^ (unsigned)(gpay & 0xFFFFFFu));
      if (lane < 3){
        float cv = san(pc[(bN + (size_t)w)*3 + lane]);
        s_res[par][lane] = cv;
        if (s==0) g_samp[((size_t)b*KSAMP + k)*3 + lane] = cv;
      }
      // release: s_res writes ordered before flag (workgroup scope)
      if (lane==0)
        __hip_atomic_store(&s_flag[par], k, __ATOMIC_RELEASE, __HIP_MEMORY_SCOPE_WORKGROUP);
      lx = s_res[par][0]; ly = s_res[par][1]; lz = s_res[par][2];
    } else {
      // data-driven wait: resume the instant the flag lands (no block barrier)
      while (__hip_atomic_load(&s_flag[par], __ATOMIC_ACQUIRE, __HIP_MEMORY_SCOPE_WORKGROUP) != k)
        ;
      lx = s_res[par][0]; ly = s_res[par][1]; lz = s_res[par][2];
    }
  }
}

// ---------------- normalize + Fourier encode ----------------
template<int OP>  // 0 sum, 1 max, 2 min
__device__ __forceinline__ float blk_red(float v, float* s4){
  int tid = threadIdx.x;
#pragma unroll
  for (int off=32; off; off>>=1){
    float o = __shfl_down(v, off);
    v = (OP==0) ? v+o : ((OP==1) ? fmaxf(v,o) : fminf(v,o));
  }
  if ((tid&63)==0) s4[tid>>6] = v;
  __syncthreads();
  float r0=s4[0], r1=s4[1], r2=s4[2], r3=s4[3];
  float r = (OP==0) ? ((r0+r1)+(r2+r3))
          : ((OP==1) ? fmaxf(fmaxf(r0,r1),fmaxf(r2,r3))
                     : fminf(fminf(r0,r1),fminf(r2,r3)));
  __syncthreads();
  return r;
}

__global__ __launch_bounds__(256) void norm_encode(){
  __shared__ float s4[4];
  int b = blockIdx.x, k = threadIdx.x;
  const float* sp = &g_samp[((size_t)b*KSAMP + k)*3];
  float x = sp[0], y = sp[1], z = sp[2];

  float cx = blk_red<0>(x, s4) * (1.0f/KSAMP);
  float cy = blk_red<0>(y, s4) * (1.0f/KSAMP);
  float cz = blk_red<0>(z, s4) * (1.0f/KSAMP);

  float ux = __fsub_rn(x,cx), uy = __fsub_rn(y,cy), uz = __fsub_rn(z,cz);

  float mxx = blk_red<1>(ux, s4), mnx = blk_red<2>(ux, s4);
  float mxy = blk_red<1>(uy, s4), mny = blk_red<2>(uy, s4);
  float mxz = blk_red<1>(uz, s4), mnz = blk_red<2>(uz, s4);
  float bx = __fsub_rn(mxx,mnx), by = __fsub_rn(mxy,mny), bz = __fsub_rn(mxz,mnz);
  float md = fmaxf(fmaxf(bx,by),bz);
  float scale = (md > 1e-8f) ? md : 1.0f;

  float n3[3] = { __fdiv_rn(ux,scale), __fdiv_rn(uy,scale), __fdiv_rn(uz,scale) };

  float* e = &g_enc[((size_t)b*KSAMP + k)*INDIM];
#pragma unroll
  for (int c=0;c<3;c++){
    float base = n3[c];
#pragma unroll
    for (int f=0; f<NF; f++){
      float t = __fmul_rn(base, (float)(1<<f));
      float a = __fmul_rn(t, PI_F);
      e[c*2*NF + f*2 + 0] = sinf(a);
      e[c*2*NF + f*2 + 1] = cosf(a);
    }
  }
}

// ---------------- GEMM ----------------
__global__ __launch_bounds__(256) void gemm_kernel(const float* __restrict__ bias,
                                                   float* __restrict__ out){
  __shared__ float s_enc[4*INDIM];
  int blk = blockIdx.x, tid = threadIdx.x;
  int row0 = blk*4;                         // 4 (b,k) rows per block
  if (tid < 4*INDIM) s_enc[tid] = g_enc[(size_t)row0*INDIM + tid];
  __syncthreads();

  float acc[4][3] = {};
  for (int d=0; d<INDIM; d++){
    float w0 = g_Wt[d*HID + tid];
    float w1 = g_Wt[d*HID + tid + 256];
    float w2 = g_Wt[d*HID + tid + 512];
#pragma unroll
    for (int r=0;r<4;r++){
      float ev = s_enc[r*INDIM + d];
      acc[r][0] = fmaf(ev, w0, acc[r][0]);
      acc[r][1] = fmaf(ev, w1, acc[r][1]);
      acc[r][2] = fmaf(ev, w2, acc[r][2]);
    }
  }
  float b0=bias[tid], b1=bias[tid+256], b2=bias[tid+512];
#pragma unroll
  for (int r=0;r<4;r++){
    size_t o = (size_t)(row0+r)*HID;
    out[o+tid]     = acc[r][0]+b0;
    out[o+tid+256] = acc[r][1]+b1;
    out[o+tid+512] = acc[r][2]+b2;
  }
}

// ---------------- launch ----------------
extern "C" void kernel_launch(void* const* d_in, const int* in_sizes, int n_in,
                              void* d_out, int out_size, void* d_ws, size_t ws_size,
                              hipStream_t stream){
  const float* pc   = (const float*)d_in[0];
  const float* W    = (const float*)d_in[1];
  const float* bias = (const float*)d_in[2];
  float* out = (float*)d_out;

  region_prepass<<<1024, 256, 0, stream>>>(pc);
  wtrans        <<<(INDIM*HID)/256, 256, 0, stream>>>(W);

  void* args[] = { (void*)&pc };
  hipLaunchCooperativeKernel((void*)fps_kernel, dim3(BATCH*NBLK_PER_B), dim3(1024),
                             args, 0, stream);

  norm_encode<<<BATCH, KSAMP, 0, stream>>>();
  gemm_kernel<<<(BATCH*KSAMP)/4, 256, 0, stream>>>(bias, out);
}